// Round 1
// baseline (1798.136 us; speedup 1.0000x reference)
//
#include <hip/hip_runtime.h>
#include <hip/hip_bf16.h>
#include <math.h>

#define N_ATOMS 8192
#define B_BATCH 64
#define E_EDGES 262144
#define S_SPEC 4
#define NMAX 8
#define PS_DIM 4096
#define H1_DIM 1024
#define CUTR 5.0f
#define PI_F 3.14159265358979f

typedef __bf16 bf16;
typedef bf16 bf16x8 __attribute__((ext_vector_type(8)));
typedef float floatx4 __attribute__((ext_vector_type(4)));

// ---------------------------------------------------------------- edge kernel
// One thread per edge: compute R[8] (x) Y[16] and atomically accumulate into
// c[(i*S + numbers[j]) * 128 + n*16 + a].  Skips edges with r >= CUT (fc==0).
__global__ __launch_bounds__(256) void edge_kernel(
    const float* __restrict__ pos, const float* __restrict__ cells,
    const int* __restrict__ numbers, const int* __restrict__ ei,
    const float* __restrict__ eo, const int* __restrict__ batch,
    float* __restrict__ c)
{
    int e = blockIdx.x * 256 + threadIdx.x;
    if (e >= E_EDGES) return;
    int i = ei[e];
    int j = ei[E_EDGES + e];
    int b = batch[i];
    const float* cell = cells + b * 9;
    float o0 = eo[e * 3 + 0], o1 = eo[e * 3 + 1], o2 = eo[e * 3 + 2];
    float rv[3];
    #pragma unroll
    for (int d = 0; d < 3; ++d) {
        float shift = o0 * cell[0 * 3 + d] + o1 * cell[1 * 3 + d] + o2 * cell[2 * 3 + d];
        rv[d] = pos[j * 3 + d] - pos[i * 3 + d] + shift;
    }
    float r2 = rv[0] * rv[0] + rv[1] * rv[1] + rv[2] * rv[2] + 1e-12f;
    float r = sqrtf(r2);
    if (r >= CUTR) return;   // fc == 0 -> zero contribution

    float a1 = PI_F * r / CUTR;
    float s1, c1;
    __sincosf(a1, &s1, &c1);
    float fc = 0.5f * (c1 + 1.0f);
    float inv_r = 1.0f / r;
    float x = rv[0] * inv_r, y = rv[1] * inv_r, z = rv[2] * inv_r;
    float x2 = x * x, y2 = y * y, z2 = z * z;

    float Y[16];
    Y[0] = 0.28209479f;
    Y[1] = 0.48860251f * y;
    Y[2] = 0.48860251f * z;
    Y[3] = 0.48860251f * x;
    Y[4] = 1.09254843f * x * y;
    Y[5] = 1.09254843f * y * z;
    Y[6] = 0.31539157f * (3.0f * z2 - 1.0f);
    Y[7] = 1.09254843f * x * z;
    Y[8] = 0.54627422f * (x2 - y2);
    Y[9] = 0.59004359f * y * (3.0f * x2 - y2);
    Y[10] = 2.89061144f * x * y * z;
    Y[11] = 0.45704579f * y * (5.0f * z2 - 1.0f);
    Y[12] = 0.37317633f * z * (5.0f * z2 - 3.0f);
    Y[13] = 0.45704579f * x * (5.0f * z2 - 1.0f);
    Y[14] = 1.44530572f * z * (x2 - y2);
    Y[15] = 0.59004359f * x * (x2 - 3.0f * y2);

    // R[n] = fc * sin((n+1)*a1) / r  via angle-addition recurrence
    float R[NMAX];
    float sn = s1, cn = c1;
    float fcr = fc * inv_r;
    R[0] = fcr * sn;
    #pragma unroll
    for (int n = 1; n < NMAX; ++n) {
        float sn1 = sn * c1 + cn * s1;
        float cn1 = cn * c1 - sn * s1;
        sn = sn1; cn = cn1;
        R[n] = fcr * sn;
    }

    int sp = numbers[j];
    float* base = c + ((size_t)i * S_SPEC + sp) * 128;
    #pragma unroll
    for (int n = 0; n < NMAX; ++n) {
        float rn = R[n];
        #pragma unroll
        for (int a = 0; a < 16; ++a) {
            atomicAdd(base + n * 16 + a, rn * Y[a]);
        }
    }
}

// ------------------------------------------------- fp32 -> bf16 transpose (Wt[n][k] = W[k][n])
__global__ __launch_bounds__(256) void transpose_convert(
    const float* __restrict__ W, bf16* __restrict__ Wt, int K, int Nc)
{
    __shared__ float t[32][33];
    int k0 = blockIdx.x * 32, n0 = blockIdx.y * 32;
    int tx = threadIdx.x & 31, ty = threadIdx.x >> 5;  // ty in [0,8)
    #pragma unroll
    for (int r = 0; r < 32; r += 8)
        t[ty + r][tx] = W[(size_t)(k0 + ty + r) * Nc + n0 + tx];
    __syncthreads();
    #pragma unroll
    for (int r = 0; r < 32; r += 8) {
        int nl = ty + r;
        Wt[(size_t)(n0 + nl) * K + k0 + tx] = (bf16)t[tx][nl];
    }
}

// ------------------------------------------------- per-atom PS + layernorm + psl
__global__ __launch_bounds__(256) void atom_ps_kernel(
    const float* __restrict__ c, const float* __restrict__ gamma,
    const float* __restrict__ beta, const float* __restrict__ Wps,
    bf16* __restrict__ psn, float* __restrict__ psl)
{
    int atom = blockIdx.x;
    int t = threadIdx.x;
    __shared__ float cl[512];
    __shared__ float red[8];
    __shared__ float red2[4];

    const float* ca = c + (size_t)atom * 512;
    ((float2*)cl)[t] = ((const float2*)ca)[t];
    __syncthreads();

    int y = t & 31;
    int xb = t >> 5;
    float cy[16];
    #pragma unroll
    for (int m = 0; m < 16; ++m) cy[m] = cl[y * 16 + m];

    float ps[4][4];
    float sum = 0.0f, sumsq = 0.0f;
    #pragma unroll
    for (int q = 0; q < 4; ++q) {
        int x = xb + 8 * q;
        const float* cx = &cl[x * 16];
        float s0 = cx[0] * cy[0];
        float s1 = 0.0f, s2 = 0.0f, s3 = 0.0f;
        #pragma unroll
        for (int m = 1; m < 4; ++m) s1 += cx[m] * cy[m];
        #pragma unroll
        for (int m = 4; m < 9; ++m) s2 += cx[m] * cy[m];
        #pragma unroll
        for (int m = 9; m < 16; ++m) s3 += cx[m] * cy[m];
        ps[q][0] = s0; ps[q][1] = s1; ps[q][2] = s2; ps[q][3] = s3;
        sum += s0 + s1 + s2 + s3;
        sumsq += s0 * s0 + s1 * s1 + s2 * s2 + s3 * s3;
    }
    #pragma unroll
    for (int o = 32; o > 0; o >>= 1) {
        sum += __shfl_down(sum, o);
        sumsq += __shfl_down(sumsq, o);
    }
    int wv = t >> 6;
    if ((t & 63) == 0) { red[wv] = sum; red[4 + wv] = sumsq; }
    __syncthreads();
    float tot = red[0] + red[1] + red[2] + red[3];
    float totsq = red[4] + red[5] + red[6] + red[7];
    float mu = tot * (1.0f / PS_DIM);
    float var = totsq * (1.0f / PS_DIM) - mu * mu;
    float inv = rsqrtf(var + 1e-5f);

    float pacc = 0.0f;
    #pragma unroll
    for (int q = 0; q < 4; ++q) {
        int p = t + 256 * q;
        float4 g = *(const float4*)(gamma + p * 4);
        float4 bt = *(const float4*)(beta + p * 4);
        float4 w = *(const float4*)(Wps + p * 4);
        float v0 = (ps[q][0] - mu) * inv * g.x + bt.x;
        float v1 = (ps[q][1] - mu) * inv * g.y + bt.y;
        float v2 = (ps[q][2] - mu) * inv * g.z + bt.z;
        float v3 = (ps[q][3] - mu) * inv * g.w + bt.w;
        pacc += v0 * w.x + v1 * w.y + v2 * w.z + v3 * w.w;
        union { bf16 bb[4]; ushort4 u; } pk;
        pk.bb[0] = (bf16)v0; pk.bb[1] = (bf16)v1; pk.bb[2] = (bf16)v2; pk.bb[3] = (bf16)v3;
        *(ushort4*)(psn + (size_t)atom * PS_DIM + p * 4) = pk.u;
    }
    #pragma unroll
    for (int o = 32; o > 0; o >>= 1) pacc += __shfl_down(pacc, o);
    if ((t & 63) == 0) red2[wv] = pacc;
    __syncthreads();
    if (t == 0) psl[atom] = red2[0] + red2[1] + red2[2] + red2[3];
}

// ------------------------------------------------- bf16 MFMA GEMM: H = act(A @ Bt^T)
// A: M x K row-major bf16; Bt: Nc x K row-major bf16; H: M x Nc bf16.
template<bool SILU>
__global__ __launch_bounds__(256) void gemm_bt_kernel(
    const bf16* __restrict__ A, const bf16* __restrict__ Bt,
    bf16* __restrict__ H, int M, int Nc, int K)
{
    __shared__ bf16 As[128 * 32];
    __shared__ bf16 Bs[128 * 32];
    int tid = threadIdx.x;
    int bm = blockIdx.x, bn = blockIdx.y;
    int wave = tid >> 6, lane = tid & 63;
    int wm = (wave >> 1) * 64, wn = (wave & 1) * 64;
    int lm = lane & 15, quad = lane >> 4;

    floatx4 acc[4][4] = {};
    const int rowA0 = bm * 128, rowB0 = bn * 128;

    for (int k0 = 0; k0 < K; k0 += 32) {
        #pragma unroll
        for (int s = 0; s < 2; ++s) {
            int L = tid + s * 256;            // 512 16B-chunks per tile
            int row = L >> 2, ch = (L & 3) * 8;
            *(uint4*)(&As[row * 32 + ch]) =
                *(const uint4*)(&A[(size_t)(rowA0 + row) * K + k0 + ch]);
            *(uint4*)(&Bs[row * 32 + ch]) =
                *(const uint4*)(&Bt[(size_t)(rowB0 + row) * K + k0 + ch]);
        }
        __syncthreads();
        bf16x8 af[4], bf[4];
        #pragma unroll
        for (int mi = 0; mi < 4; ++mi)
            af[mi] = *(const bf16x8*)(&As[(wm + mi * 16 + lm) * 32 + quad * 8]);
        #pragma unroll
        for (int ni = 0; ni < 4; ++ni)
            bf[ni] = *(const bf16x8*)(&Bs[(wn + ni * 16 + lm) * 32 + quad * 8]);
        #pragma unroll
        for (int mi = 0; mi < 4; ++mi)
            #pragma unroll
            for (int ni = 0; ni < 4; ++ni)
                acc[mi][ni] = __builtin_amdgcn_mfma_f32_16x16x32_bf16(
                    af[mi], bf[ni], acc[mi][ni], 0, 0, 0);
        __syncthreads();
    }

    #pragma unroll
    for (int mi = 0; mi < 4; ++mi) {
        #pragma unroll
        for (int ni = 0; ni < 4; ++ni) {
            #pragma unroll
            for (int r = 0; r < 4; ++r) {
                int row = rowA0 + wm + mi * 16 + quad * 4 + r;
                int col = rowB0 + wn + ni * 16 + lm;
                float v = acc[mi][ni][r];
                if (SILU) v = v / (1.0f + __expf(-v));
                H[(size_t)row * Nc + col] = (bf16)v;
            }
        }
    }
}

// ------------------------------------------------- psnn = h2 @ W3 ; e_atom = psl + psnn
__global__ __launch_bounds__(256) void psnn_kernel(
    const bf16* __restrict__ h2, const float* __restrict__ W3,
    const float* __restrict__ psl, float* __restrict__ e_atom)
{
    int atom = blockIdx.x * 4 + (threadIdx.x >> 6);
    int lane = threadIdx.x & 63;
    const bf16* h = h2 + (size_t)atom * H1_DIM;
    float s = 0.0f;
    #pragma unroll
    for (int q = 0; q < 16; ++q) {
        int k = lane + 64 * q;
        s += (float)h[k] * W3[k];
    }
    #pragma unroll
    for (int o = 32; o > 0; o >>= 1) s += __shfl_down(s, o);
    if (lane == 0) e_atom[atom] = psl[atom] + s;
}

// ------------------------------------------------- per-batch finalize
__global__ __launch_bounds__(128) void final_kernel(
    const float* __restrict__ e_atom, const int* __restrict__ numbers,
    const float* __restrict__ Wcomp, float* __restrict__ out)
{
    int b = blockIdx.x, t = threadIdx.x;  // 128 threads = atoms per batch
    __shared__ float sh[2];
    __shared__ int cnt[S_SPEC];
    if (t < S_SPEC) cnt[t] = 0;
    __syncthreads();
    int a = b * 128 + t;
    float e = e_atom[a];
    atomicAdd(&cnt[numbers[a]], 1);
    #pragma unroll
    for (int o = 32; o > 0; o >>= 1) e += __shfl_down(e, o);
    if ((t & 63) == 0) sh[t >> 6] = e;
    __syncthreads();
    if (t == 0) {
        float r = (sh[0] + sh[1]) * (1.0f / 128.0f);
        #pragma unroll
        for (int s = 0; s < S_SPEC; ++s) r += (float)cnt[s] * Wcomp[s];
        out[b] = r;
    }
}

extern "C" void kernel_launch(void* const* d_in, const int* in_sizes, int n_in,
                              void* d_out, int out_size, void* d_ws, size_t ws_size,
                              hipStream_t stream)
{
    const float* positions = (const float*)d_in[0];
    const float* cells     = (const float*)d_in[1];
    const int*   numbers   = (const int*)d_in[2];
    const int*   ei        = (const int*)d_in[3];
    const float* eo        = (const float*)d_in[4];
    const int*   batch     = (const int*)d_in[5];
    const float* gamma     = (const float*)d_in[6];
    const float* beta      = (const float*)d_in[7];
    const float* W_ps      = (const float*)d_in[8];
    const float* W1        = (const float*)d_in[9];
    const float* W2        = (const float*)d_in[10];
    const float* W3        = (const float*)d_in[11];
    const float* W_comp    = (const float*)d_in[12];
    float* out = (float*)d_out;

    char* ws = (char*)d_ws;
    float* c    = (float*)ws;  ws += (size_t)N_ATOMS * S_SPEC * 128 * 4;   // 16 MB
    bf16*  psn  = (bf16*)ws;   ws += (size_t)N_ATOMS * PS_DIM * 2;         // 64 MB
    bf16*  h1   = (bf16*)ws;   ws += (size_t)N_ATOMS * H1_DIM * 2;         // 16 MB
    bf16*  h2   = (bf16*)ws;   ws += (size_t)N_ATOMS * H1_DIM * 2;         // 16 MB
    bf16*  Wt1  = (bf16*)ws;   ws += (size_t)H1_DIM * PS_DIM * 2;          // 8 MB
    bf16*  Wt2  = (bf16*)ws;   ws += (size_t)H1_DIM * H1_DIM * 2;          // 2 MB
    float* psl  = (float*)ws;  ws += (size_t)N_ATOMS * 4;
    float* e_at = (float*)ws;  ws += (size_t)N_ATOMS * 4;

    hipMemsetAsync(c, 0, (size_t)N_ATOMS * S_SPEC * 128 * 4, stream);

    edge_kernel<<<E_EDGES / 256, 256, 0, stream>>>(
        positions, cells, numbers, ei, eo, batch, c);

    transpose_convert<<<dim3(PS_DIM / 32, H1_DIM / 32), 256, 0, stream>>>(
        W1, Wt1, PS_DIM, H1_DIM);
    transpose_convert<<<dim3(H1_DIM / 32, H1_DIM / 32), 256, 0, stream>>>(
        W2, Wt2, H1_DIM, H1_DIM);

    atom_ps_kernel<<<N_ATOMS, 256, 0, stream>>>(c, gamma, beta, W_ps, psn, psl);

    gemm_bt_kernel<true><<<dim3(N_ATOMS / 128, H1_DIM / 128), 256, 0, stream>>>(
        psn, Wt1, h1, N_ATOMS, H1_DIM, PS_DIM);
    gemm_bt_kernel<true><<<dim3(N_ATOMS / 128, H1_DIM / 128), 256, 0, stream>>>(
        h1, Wt2, h2, N_ATOMS, H1_DIM, H1_DIM);

    psnn_kernel<<<N_ATOMS / 4, 256, 0, stream>>>(h2, W3, psl, e_at);
    final_kernel<<<B_BATCH, 128, 0, stream>>>(e_at, numbers, W_comp, out);
}

// Round 2
// 476.132 us; speedup vs baseline: 3.7765x; 3.7765x over previous
//
#include <hip/hip_runtime.h>
#include <hip/hip_bf16.h>
#include <math.h>

#define N_ATOMS 8192
#define B_BATCH 64
#define E_EDGES 262144
#define S_SPEC 4
#define NMAX 8
#define PS_DIM 4096
#define H1_DIM 1024
#define CUTR 5.0f
#define PI_F 3.14159265358979f

typedef __bf16 bf16;
typedef bf16 bf16x8 __attribute__((ext_vector_type(8)));
typedef float floatx4 __attribute__((ext_vector_type(4)));

// ---------------------------------------------------------------- histogram
// Count edges per target atom i (unfiltered; cutoff filter happens in scatter).
__global__ __launch_bounds__(256) void hist_kernel(
    const int* __restrict__ ei, int* __restrict__ cnt)
{
    int e = blockIdx.x * 256 + threadIdx.x;
    atomicAdd(&cnt[ei[e]], 1);
}

// ---------------------------------------------------------------- scan
// Exclusive prefix sum of cnt[8192] -> start[8192]; cursor = copy of start
// (scatter bumps cursor; after scatter cursor[i] == end of bucket i).
__global__ __launch_bounds__(1024) void scan_kernel(
    const int* __restrict__ cnt, int* __restrict__ start, int* __restrict__ cursor)
{
    int t = threadIdx.x;
    int v[8];
    int tot = 0;
    #pragma unroll
    for (int k = 0; k < 8; ++k) { v[k] = cnt[t * 8 + k]; tot += v[k]; }
    int lane = t & 63, wv = t >> 6;
    int inc = tot;
    #pragma unroll
    for (int o = 1; o < 64; o <<= 1) {
        int n = __shfl_up(inc, o);
        if (lane >= o) inc += n;
    }
    __shared__ int wsum[16];
    __shared__ int woff[16];
    if (lane == 63) wsum[wv] = inc;
    __syncthreads();
    if (t == 0) {
        int a = 0;
        for (int w = 0; w < 16; ++w) { woff[w] = a; a += wsum[w]; }
    }
    __syncthreads();
    int ex = woff[wv] + inc - tot;
    #pragma unroll
    for (int k = 0; k < 8; ++k) {
        start[t * 8 + k] = ex;
        cursor[t * 8 + k] = ex;
        ex += v[k];
    }
}

// ---------------------------------------------------------------- scatter
// Compute rvec per edge, drop r>=CUT, place (rvec, species) into bucket[i].
__global__ __launch_bounds__(256) void scatter_kernel(
    const float* __restrict__ pos, const float* __restrict__ cells,
    const int* __restrict__ numbers, const int* __restrict__ ei,
    const float* __restrict__ eo, const int* __restrict__ batch,
    int* __restrict__ cursor, float4* __restrict__ bucket)
{
    int e = blockIdx.x * 256 + threadIdx.x;
    int i = ei[e];
    int j = ei[E_EDGES + e];
    int b = batch[i];
    const float* cell = cells + b * 9;
    float o0 = eo[e * 3 + 0], o1 = eo[e * 3 + 1], o2 = eo[e * 3 + 2];
    float rv[3];
    #pragma unroll
    for (int d = 0; d < 3; ++d) {
        float shift = o0 * cell[0 * 3 + d] + o1 * cell[1 * 3 + d] + o2 * cell[2 * 3 + d];
        rv[d] = pos[j * 3 + d] - pos[i * 3 + d] + shift;
    }
    float r2 = rv[0] * rv[0] + rv[1] * rv[1] + rv[2] * rv[2] + 1e-12f;
    if (r2 >= CUTR * CUTR) return;   // fc == 0 -> zero contribution
    int sp = numbers[j];
    int slot = atomicAdd(&cursor[i], 1);
    bucket[slot] = make_float4(rv[0], rv[1], rv[2], __int_as_float(sp));
}

// ---------------------------------------------------------------- accumulate
// One wave per atom (4 waves/block). Lane-per-edge; R[8] (x) Y[16] accumulated
// into a per-wave LDS region with ds_add_f32; single coalesced write of c[512].
__global__ __launch_bounds__(256) void accum_kernel(
    const float4* __restrict__ bucket, const int* __restrict__ start,
    const int* __restrict__ endp, float* __restrict__ c)
{
    __shared__ float acc[4 * 512];
    int wv = threadIdx.x >> 6, lane = threadIdx.x & 63;
    int atom = blockIdx.x * 4 + wv;
    float* my = acc + wv * 512;

    float4* accv = (float4*)my;
    accv[lane] = make_float4(0.f, 0.f, 0.f, 0.f);
    accv[lane + 64] = make_float4(0.f, 0.f, 0.f, 0.f);
    __syncthreads();

    int s0 = start[atom], s1 = endp[atom];
    for (int base = s0; base < s1; base += 64) {
        int idx = base + lane;
        if (idx < s1) {
            float4 d = bucket[idx];
            float r2 = d.x * d.x + d.y * d.y + d.z * d.z + 1e-12f;
            float r = sqrtf(r2);
            float a1 = PI_F * r / CUTR;
            float s1f, c1f;
            __sincosf(a1, &s1f, &c1f);
            float fc = 0.5f * (c1f + 1.0f);
            float inv_r = 1.0f / r;
            float x = d.x * inv_r, y = d.y * inv_r, z = d.z * inv_r;
            float x2 = x * x, y2 = y * y, z2 = z * z;

            float Y[16];
            Y[0] = 0.28209479f;
            Y[1] = 0.48860251f * y;
            Y[2] = 0.48860251f * z;
            Y[3] = 0.48860251f * x;
            Y[4] = 1.09254843f * x * y;
            Y[5] = 1.09254843f * y * z;
            Y[6] = 0.31539157f * (3.0f * z2 - 1.0f);
            Y[7] = 1.09254843f * x * z;
            Y[8] = 0.54627422f * (x2 - y2);
            Y[9] = 0.59004359f * y * (3.0f * x2 - y2);
            Y[10] = 2.89061144f * x * y * z;
            Y[11] = 0.45704579f * y * (5.0f * z2 - 1.0f);
            Y[12] = 0.37317633f * z * (5.0f * z2 - 3.0f);
            Y[13] = 0.45704579f * x * (5.0f * z2 - 1.0f);
            Y[14] = 1.44530572f * z * (x2 - y2);
            Y[15] = 0.59004359f * x * (x2 - 3.0f * y2);

            float R[NMAX];
            float sn = s1f, cn = c1f;
            float fcr = fc * inv_r;
            R[0] = fcr * sn;
            #pragma unroll
            for (int n = 1; n < NMAX; ++n) {
                float sn1 = sn * c1f + cn * s1f;
                float cn1 = cn * c1f - sn * s1f;
                sn = sn1; cn = cn1;
                R[n] = fcr * sn;
            }

            int sp = __float_as_int(d.w);
            float* a0 = my + sp * 128;
            #pragma unroll
            for (int n = 0; n < NMAX; ++n) {
                float rn = R[n];
                #pragma unroll
                for (int a = 0; a < 16; ++a)
                    atomicAdd(a0 + n * 16 + a, rn * Y[a]);
            }
        }
    }
    __syncthreads();

    float4* dst = (float4*)(c + (size_t)atom * 512);
    dst[lane] = accv[lane];
    dst[lane + 64] = accv[lane + 64];
}

// ------------------------------------------------- fp32 -> bf16 transpose (Wt[n][k] = W[k][n])
__global__ __launch_bounds__(256) void transpose_convert(
    const float* __restrict__ W, bf16* __restrict__ Wt, int K, int Nc)
{
    __shared__ float t[32][33];
    int k0 = blockIdx.x * 32, n0 = blockIdx.y * 32;
    int tx = threadIdx.x & 31, ty = threadIdx.x >> 5;  // ty in [0,8)
    #pragma unroll
    for (int r = 0; r < 32; r += 8)
        t[ty + r][tx] = W[(size_t)(k0 + ty + r) * Nc + n0 + tx];
    __syncthreads();
    #pragma unroll
    for (int r = 0; r < 32; r += 8) {
        int nl = ty + r;
        Wt[(size_t)(n0 + nl) * K + k0 + tx] = (bf16)t[tx][nl];
    }
}

// ------------------------------------------------- per-atom PS + layernorm + psl
__global__ __launch_bounds__(256) void atom_ps_kernel(
    const float* __restrict__ c, const float* __restrict__ gamma,
    const float* __restrict__ beta, const float* __restrict__ Wps,
    bf16* __restrict__ psn, float* __restrict__ psl)
{
    int atom = blockIdx.x;
    int t = threadIdx.x;
    __shared__ float cl[512];
    __shared__ float red[8];
    __shared__ float red2[4];

    const float* ca = c + (size_t)atom * 512;
    ((float2*)cl)[t] = ((const float2*)ca)[t];
    __syncthreads();

    int y = t & 31;
    int xb = t >> 5;
    float cy[16];
    #pragma unroll
    for (int m = 0; m < 16; ++m) cy[m] = cl[y * 16 + m];

    float ps[4][4];
    float sum = 0.0f, sumsq = 0.0f;
    #pragma unroll
    for (int q = 0; q < 4; ++q) {
        int x = xb + 8 * q;
        const float* cx = &cl[x * 16];
        float s0 = cx[0] * cy[0];
        float s1 = 0.0f, s2 = 0.0f, s3 = 0.0f;
        #pragma unroll
        for (int m = 1; m < 4; ++m) s1 += cx[m] * cy[m];
        #pragma unroll
        for (int m = 4; m < 9; ++m) s2 += cx[m] * cy[m];
        #pragma unroll
        for (int m = 9; m < 16; ++m) s3 += cx[m] * cy[m];
        ps[q][0] = s0; ps[q][1] = s1; ps[q][2] = s2; ps[q][3] = s3;
        sum += s0 + s1 + s2 + s3;
        sumsq += s0 * s0 + s1 * s1 + s2 * s2 + s3 * s3;
    }
    #pragma unroll
    for (int o = 32; o > 0; o >>= 1) {
        sum += __shfl_down(sum, o);
        sumsq += __shfl_down(sumsq, o);
    }
    int wv = t >> 6;
    if ((t & 63) == 0) { red[wv] = sum; red[4 + wv] = sumsq; }
    __syncthreads();
    float tot = red[0] + red[1] + red[2] + red[3];
    float totsq = red[4] + red[5] + red[6] + red[7];
    float mu = tot * (1.0f / PS_DIM);
    float var = totsq * (1.0f / PS_DIM) - mu * mu;
    float inv = rsqrtf(var + 1e-5f);

    float pacc = 0.0f;
    #pragma unroll
    for (int q = 0; q < 4; ++q) {
        int p = t + 256 * q;
        float4 g = *(const float4*)(gamma + p * 4);
        float4 bt = *(const float4*)(beta + p * 4);
        float4 w = *(const float4*)(Wps + p * 4);
        float v0 = (ps[q][0] - mu) * inv * g.x + bt.x;
        float v1 = (ps[q][1] - mu) * inv * g.y + bt.y;
        float v2 = (ps[q][2] - mu) * inv * g.z + bt.z;
        float v3 = (ps[q][3] - mu) * inv * g.w + bt.w;
        pacc += v0 * w.x + v1 * w.y + v2 * w.z + v3 * w.w;
        union { bf16 bb[4]; ushort4 u; } pk;
        pk.bb[0] = (bf16)v0; pk.bb[1] = (bf16)v1; pk.bb[2] = (bf16)v2; pk.bb[3] = (bf16)v3;
        *(ushort4*)(psn + (size_t)atom * PS_DIM + p * 4) = pk.u;
    }
    #pragma unroll
    for (int o = 32; o > 0; o >>= 1) pacc += __shfl_down(pacc, o);
    if ((t & 63) == 0) red2[wv] = pacc;
    __syncthreads();
    if (t == 0) psl[atom] = red2[0] + red2[1] + red2[2] + red2[3];
}

// ------------------------------------------------- bf16 MFMA GEMM: H = act(A @ Bt^T)
// A: M x K row-major bf16; Bt: Nc x K row-major bf16; H: M x Nc bf16.
template<bool SILU>
__global__ __launch_bounds__(256) void gemm_bt_kernel(
    const bf16* __restrict__ A, const bf16* __restrict__ Bt,
    bf16* __restrict__ H, int M, int Nc, int K)
{
    __shared__ bf16 As[128 * 32];
    __shared__ bf16 Bs[128 * 32];
    int tid = threadIdx.x;
    int bm = blockIdx.x, bn = blockIdx.y;
    int wave = tid >> 6, lane = tid & 63;
    int wm = (wave >> 1) * 64, wn = (wave & 1) * 64;
    int lm = lane & 15, quad = lane >> 4;

    floatx4 acc[4][4] = {};
    const int rowA0 = bm * 128, rowB0 = bn * 128;

    for (int k0 = 0; k0 < K; k0 += 32) {
        #pragma unroll
        for (int s = 0; s < 2; ++s) {
            int L = tid + s * 256;            // 512 16B-chunks per tile
            int row = L >> 2, ch = (L & 3) * 8;
            *(uint4*)(&As[row * 32 + ch]) =
                *(const uint4*)(&A[(size_t)(rowA0 + row) * K + k0 + ch]);
            *(uint4*)(&Bs[row * 32 + ch]) =
                *(const uint4*)(&Bt[(size_t)(rowB0 + row) * K + k0 + ch]);
        }
        __syncthreads();
        bf16x8 af[4], bfr[4];
        #pragma unroll
        for (int mi = 0; mi < 4; ++mi)
            af[mi] = *(const bf16x8*)(&As[(wm + mi * 16 + lm) * 32 + quad * 8]);
        #pragma unroll
        for (int ni = 0; ni < 4; ++ni)
            bfr[ni] = *(const bf16x8*)(&Bs[(wn + ni * 16 + lm) * 32 + quad * 8]);
        #pragma unroll
        for (int mi = 0; mi < 4; ++mi)
            #pragma unroll
            for (int ni = 0; ni < 4; ++ni)
                acc[mi][ni] = __builtin_amdgcn_mfma_f32_16x16x32_bf16(
                    af[mi], bfr[ni], acc[mi][ni], 0, 0, 0);
        __syncthreads();
    }

    #pragma unroll
    for (int mi = 0; mi < 4; ++mi) {
        #pragma unroll
        for (int ni = 0; ni < 4; ++ni) {
            #pragma unroll
            for (int r = 0; r < 4; ++r) {
                int row = rowA0 + wm + mi * 16 + quad * 4 + r;
                int col = rowB0 + wn + ni * 16 + lm;
                float v = acc[mi][ni][r];
                if (SILU) v = v / (1.0f + __expf(-v));
                H[(size_t)row * Nc + col] = (bf16)v;
            }
        }
    }
}

// ------------------------------------------------- psnn = h2 @ W3 ; e_atom = psl + psnn
__global__ __launch_bounds__(256) void psnn_kernel(
    const bf16* __restrict__ h2, const float* __restrict__ W3,
    const float* __restrict__ psl, float* __restrict__ e_atom)
{
    int atom = blockIdx.x * 4 + (threadIdx.x >> 6);
    int lane = threadIdx.x & 63;
    const bf16* h = h2 + (size_t)atom * H1_DIM;
    float s = 0.0f;
    #pragma unroll
    for (int q = 0; q < 16; ++q) {
        int k = lane + 64 * q;
        s += (float)h[k] * W3[k];
    }
    #pragma unroll
    for (int o = 32; o > 0; o >>= 1) s += __shfl_down(s, o);
    if (lane == 0) e_atom[atom] = psl[atom] + s;
}

// ------------------------------------------------- per-batch finalize
__global__ __launch_bounds__(128) void final_kernel(
    const float* __restrict__ e_atom, const int* __restrict__ numbers,
    const float* __restrict__ Wcomp, float* __restrict__ out)
{
    int b = blockIdx.x, t = threadIdx.x;  // 128 threads = atoms per batch
    __shared__ float sh[2];
    __shared__ int cnt[S_SPEC];
    if (t < S_SPEC) cnt[t] = 0;
    __syncthreads();
    int a = b * 128 + t;
    float e = e_atom[a];
    atomicAdd(&cnt[numbers[a]], 1);
    #pragma unroll
    for (int o = 32; o > 0; o >>= 1) e += __shfl_down(e, o);
    if ((t & 63) == 0) sh[t >> 6] = e;
    __syncthreads();
    if (t == 0) {
        float r = (sh[0] + sh[1]) * (1.0f / 128.0f);
        #pragma unroll
        for (int s = 0; s < S_SPEC; ++s) r += (float)cnt[s] * Wcomp[s];
        out[b] = r;
    }
}

extern "C" void kernel_launch(void* const* d_in, const int* in_sizes, int n_in,
                              void* d_out, int out_size, void* d_ws, size_t ws_size,
                              hipStream_t stream)
{
    const float* positions = (const float*)d_in[0];
    const float* cells     = (const float*)d_in[1];
    const int*   numbers   = (const int*)d_in[2];
    const int*   ei        = (const int*)d_in[3];
    const float* eo        = (const float*)d_in[4];
    const int*   batch     = (const int*)d_in[5];
    const float* gamma     = (const float*)d_in[6];
    const float* beta      = (const float*)d_in[7];
    const float* W_ps      = (const float*)d_in[8];
    const float* W1        = (const float*)d_in[9];
    const float* W2        = (const float*)d_in[10];
    const float* W3        = (const float*)d_in[11];
    const float* W_comp    = (const float*)d_in[12];
    float* out = (float*)d_out;

    char* ws = (char*)d_ws;
    float* c    = (float*)ws;  ws += (size_t)N_ATOMS * S_SPEC * 128 * 4;   // 16 MB
    bf16*  psn  = (bf16*)ws;   ws += (size_t)N_ATOMS * PS_DIM * 2;         // 64 MB
    bf16*  h1   = (bf16*)ws;   ws += (size_t)N_ATOMS * H1_DIM * 2;         // 16 MB
    bf16*  h2   = (bf16*)ws;   ws += (size_t)N_ATOMS * H1_DIM * 2;         // 16 MB
    bf16*  Wt1  = (bf16*)ws;   ws += (size_t)H1_DIM * PS_DIM * 2;          // 8 MB
    bf16*  Wt2  = (bf16*)ws;   ws += (size_t)H1_DIM * H1_DIM * 2;          // 2 MB
    float* psl  = (float*)ws;  ws += (size_t)N_ATOMS * 4;
    float* e_at = (float*)ws;  ws += (size_t)N_ATOMS * 4;

    // Aliased scratch (consumed before their hosts are written):
    //  - bucket (4 MB) aliases psn  : read by accum_kernel, psn written later by atom_ps
    //  - cnt/start/cursor (96 KB) alias h1 : read through accum, h1 written later by gemm1
    float4* bucket = (float4*)psn;
    int* cnt    = (int*)h1;
    int* start  = cnt + N_ATOMS;
    int* cursor = start + N_ATOMS;

    hipMemsetAsync(cnt, 0, N_ATOMS * sizeof(int), stream);

    hist_kernel<<<E_EDGES / 256, 256, 0, stream>>>(ei, cnt);
    scan_kernel<<<1, 1024, 0, stream>>>(cnt, start, cursor);
    scatter_kernel<<<E_EDGES / 256, 256, 0, stream>>>(
        positions, cells, numbers, ei, eo, batch, cursor, bucket);
    accum_kernel<<<N_ATOMS / 4, 256, 0, stream>>>(bucket, start, cursor, c);

    transpose_convert<<<dim3(PS_DIM / 32, H1_DIM / 32), 256, 0, stream>>>(
        W1, Wt1, PS_DIM, H1_DIM);
    transpose_convert<<<dim3(H1_DIM / 32, H1_DIM / 32), 256, 0, stream>>>(
        W2, Wt2, H1_DIM, H1_DIM);

    atom_ps_kernel<<<N_ATOMS, 256, 0, stream>>>(c, gamma, beta, W_ps, psn, psl);

    gemm_bt_kernel<true><<<dim3(N_ATOMS / 128, H1_DIM / 128), 256, 0, stream>>>(
        psn, Wt1, h1, N_ATOMS, H1_DIM, PS_DIM);
    gemm_bt_kernel<true><<<dim3(N_ATOMS / 128, H1_DIM / 128), 256, 0, stream>>>(
        h1, Wt2, h2, N_ATOMS, H1_DIM, H1_DIM);

    psnn_kernel<<<N_ATOMS / 4, 256, 0, stream>>>(h2, W3, psl, e_at);
    final_kernel<<<B_BATCH, 128, 0, stream>>>(e_at, numbers, W_comp, out);
}

// Round 3
// 347.117 us; speedup vs baseline: 5.1802x; 1.3717x over previous
//
#include <hip/hip_runtime.h>
#include <hip/hip_bf16.h>
#include <math.h>

#define N_ATOMS 8192
#define B_BATCH 64
#define E_EDGES 262144
#define S_SPEC 4
#define NMAX 8
#define PS_DIM 4096
#define H1_DIM 1024
#define CUTR 5.0f
#define PI_F 3.14159265358979f

typedef __bf16 bf16;
typedef bf16 bf16x8 __attribute__((ext_vector_type(8)));
typedef float floatx4 __attribute__((ext_vector_type(4)));

// async global->LDS, 16B per lane; LDS dest = wave-uniform base + lane*16
__device__ __forceinline__ void g2lds16(const void* g, void* l) {
    __builtin_amdgcn_global_load_lds(
        (const __attribute__((address_space(1))) void*)g,
        (__attribute__((address_space(3))) void*)l, 16, 0, 0);
}

// ---------------------------------------------------------------- histogram
__global__ __launch_bounds__(256) void hist_kernel(
    const int* __restrict__ ei, int* __restrict__ cnt)
{
    int e = blockIdx.x * 256 + threadIdx.x;
    atomicAdd(&cnt[ei[e]], 1);
}

// ---------------------------------------------------------------- scan
__global__ __launch_bounds__(1024) void scan_kernel(
    const int* __restrict__ cnt, int* __restrict__ start, int* __restrict__ cursor)
{
    int t = threadIdx.x;
    int v[8];
    int tot = 0;
    #pragma unroll
    for (int k = 0; k < 8; ++k) { v[k] = cnt[t * 8 + k]; tot += v[k]; }
    int lane = t & 63, wv = t >> 6;
    int inc = tot;
    #pragma unroll
    for (int o = 1; o < 64; o <<= 1) {
        int n = __shfl_up(inc, o);
        if (lane >= o) inc += n;
    }
    __shared__ int wsum[16];
    __shared__ int woff[16];
    if (lane == 63) wsum[wv] = inc;
    __syncthreads();
    if (t == 0) {
        int a = 0;
        for (int w = 0; w < 16; ++w) { woff[w] = a; a += wsum[w]; }
    }
    __syncthreads();
    int ex = woff[wv] + inc - tot;
    #pragma unroll
    for (int k = 0; k < 8; ++k) {
        start[t * 8 + k] = ex;
        cursor[t * 8 + k] = ex;
        ex += v[k];
    }
}

// ---------------------------------------------------------------- scatter
__global__ __launch_bounds__(256) void scatter_kernel(
    const float* __restrict__ pos, const float* __restrict__ cells,
    const int* __restrict__ numbers, const int* __restrict__ ei,
    const float* __restrict__ eo, const int* __restrict__ batch,
    int* __restrict__ cursor, float4* __restrict__ bucket)
{
    int e = blockIdx.x * 256 + threadIdx.x;
    int i = ei[e];
    int j = ei[E_EDGES + e];
    int b = batch[i];
    const float* cell = cells + b * 9;
    float o0 = eo[e * 3 + 0], o1 = eo[e * 3 + 1], o2 = eo[e * 3 + 2];
    float rv[3];
    #pragma unroll
    for (int d = 0; d < 3; ++d) {
        float shift = o0 * cell[0 * 3 + d] + o1 * cell[1 * 3 + d] + o2 * cell[2 * 3 + d];
        rv[d] = pos[j * 3 + d] - pos[i * 3 + d] + shift;
    }
    float r2 = rv[0] * rv[0] + rv[1] * rv[1] + rv[2] * rv[2] + 1e-12f;
    if (r2 >= CUTR * CUTR) return;   // fc == 0 -> zero contribution
    int sp = numbers[j];
    int slot = atomicAdd(&cursor[i], 1);
    bucket[slot] = make_float4(rv[0], rv[1], rv[2], __int_as_float(sp));
}

// ---------------------------------------------------------------- accumulate
// One wave per atom. Output-element ownership: lane owns c[atom*512 + lane*8 ..+7]
// (species = lane>>4, n = (lane>>1)&7, a-half = 8*(lane&1)). Edges loaded
// coalesced one-per-lane, broadcast with __shfl; zero atomics, zero barriers.
__global__ __launch_bounds__(256) void accum_kernel(
    const float4* __restrict__ bucket, const int* __restrict__ start,
    const int* __restrict__ endp, float* __restrict__ c)
{
    int wv = threadIdx.x >> 6, lane = threadIdx.x & 63;
    int atom = blockIdx.x * 4 + wv;

    int sp_l = lane >> 4;
    float nf = (float)(((lane >> 1) & 7) + 1);
    int par = lane & 1;

    float acc[8] = {};
    int s0 = start[atom], s1 = endp[atom];
    for (int base = s0; base < s1; base += 64) {
        int cnt = s1 - base; if (cnt > 64) cnt = 64;
        int idx = base + lane; if (idx >= s1) idx = s1 - 1;
        float4 d = bucket[idx];
        for (int e = 0; e < cnt; ++e) {
            float dx = __shfl(d.x, e);
            float dy = __shfl(d.y, e);
            float dz = __shfl(d.z, e);
            int sp = __float_as_int(__shfl(d.w, e));

            float r2 = dx * dx + dy * dy + dz * dz + 1e-12f;
            float r = sqrtf(r2);
            float inv_r = 1.0f / r;
            float a1 = PI_F * r * (1.0f / CUTR);
            float fc = 0.5f * (__cosf(a1) + 1.0f);
            // lane's radial basis value, masked by species match
            float rn = fc * inv_r * __sinf(nf * a1);
            rn = (sp == sp_l) ? rn : 0.0f;

            float x = dx * inv_r, y = dy * inv_r, z = dz * inv_r;
            float x2 = x * x, y2 = y * y, z2 = z * z;
            float Ys[8];
            if (par == 0) {
                Ys[0] = 0.28209479f;
                Ys[1] = 0.48860251f * y;
                Ys[2] = 0.48860251f * z;
                Ys[3] = 0.48860251f * x;
                Ys[4] = 1.09254843f * x * y;
                Ys[5] = 1.09254843f * y * z;
                Ys[6] = 0.31539157f * (3.0f * z2 - 1.0f);
                Ys[7] = 1.09254843f * x * z;
            } else {
                Ys[0] = 0.54627422f * (x2 - y2);
                Ys[1] = 0.59004359f * y * (3.0f * x2 - y2);
                Ys[2] = 2.89061144f * x * y * z;
                Ys[3] = 0.45704579f * y * (5.0f * z2 - 1.0f);
                Ys[4] = 0.37317633f * z * (5.0f * z2 - 3.0f);
                Ys[5] = 0.45704579f * x * (5.0f * z2 - 1.0f);
                Ys[6] = 1.44530572f * z * (x2 - y2);
                Ys[7] = 0.59004359f * x * (x2 - 3.0f * y2);
            }
            #pragma unroll
            for (int k = 0; k < 8; ++k) acc[k] += rn * Ys[k];
        }
    }

    float* dst = c + (size_t)atom * 512 + lane * 8;
    *(float4*)(dst + 0) = make_float4(acc[0], acc[1], acc[2], acc[3]);
    *(float4*)(dst + 4) = make_float4(acc[4], acc[5], acc[6], acc[7]);
}

// ------------------------------------------------- fp32 -> bf16 transpose (Wt[n][k] = W[k][n])
__global__ __launch_bounds__(256) void transpose_convert(
    const float* __restrict__ W, bf16* __restrict__ Wt, int K, int Nc)
{
    __shared__ float t[32][33];
    int k0 = blockIdx.x * 32, n0 = blockIdx.y * 32;
    int tx = threadIdx.x & 31, ty = threadIdx.x >> 5;  // ty in [0,8)
    #pragma unroll
    for (int r = 0; r < 32; r += 8)
        t[ty + r][tx] = W[(size_t)(k0 + ty + r) * Nc + n0 + tx];
    __syncthreads();
    #pragma unroll
    for (int r = 0; r < 32; r += 8) {
        int nl = ty + r;
        Wt[(size_t)(n0 + nl) * K + k0 + tx] = (bf16)t[tx][nl];
    }
}

// ------------------------------------------------- per-atom PS + layernorm + psl
__global__ __launch_bounds__(256) void atom_ps_kernel(
    const float* __restrict__ c, const float* __restrict__ gamma,
    const float* __restrict__ beta, const float* __restrict__ Wps,
    bf16* __restrict__ psn, float* __restrict__ psl)
{
    int atom = blockIdx.x;
    int t = threadIdx.x;
    __shared__ float cl[512];
    __shared__ float red[8];
    __shared__ float red2[4];

    const float* ca = c + (size_t)atom * 512;
    ((float2*)cl)[t] = ((const float2*)ca)[t];
    __syncthreads();

    int y = t & 31;
    int xb = t >> 5;
    float cy[16];
    #pragma unroll
    for (int m = 0; m < 16; ++m) cy[m] = cl[y * 16 + m];

    float ps[4][4];
    float sum = 0.0f, sumsq = 0.0f;
    #pragma unroll
    for (int q = 0; q < 4; ++q) {
        int x = xb + 8 * q;
        const float* cx = &cl[x * 16];
        float s0 = cx[0] * cy[0];
        float s1 = 0.0f, s2 = 0.0f, s3 = 0.0f;
        #pragma unroll
        for (int m = 1; m < 4; ++m) s1 += cx[m] * cy[m];
        #pragma unroll
        for (int m = 4; m < 9; ++m) s2 += cx[m] * cy[m];
        #pragma unroll
        for (int m = 9; m < 16; ++m) s3 += cx[m] * cy[m];
        ps[q][0] = s0; ps[q][1] = s1; ps[q][2] = s2; ps[q][3] = s3;
        sum += s0 + s1 + s2 + s3;
        sumsq += s0 * s0 + s1 * s1 + s2 * s2 + s3 * s3;
    }
    #pragma unroll
    for (int o = 32; o > 0; o >>= 1) {
        sum += __shfl_down(sum, o);
        sumsq += __shfl_down(sumsq, o);
    }
    int wv = t >> 6;
    if ((t & 63) == 0) { red[wv] = sum; red[4 + wv] = sumsq; }
    __syncthreads();
    float tot = red[0] + red[1] + red[2] + red[3];
    float totsq = red[4] + red[5] + red[6] + red[7];
    float mu = tot * (1.0f / PS_DIM);
    float var = totsq * (1.0f / PS_DIM) - mu * mu;
    float inv = rsqrtf(var + 1e-5f);

    float pacc = 0.0f;
    #pragma unroll
    for (int q = 0; q < 4; ++q) {
        int p = t + 256 * q;
        float4 g = *(const float4*)(gamma + p * 4);
        float4 bt = *(const float4*)(beta + p * 4);
        float4 w = *(const float4*)(Wps + p * 4);
        float v0 = (ps[q][0] - mu) * inv * g.x + bt.x;
        float v1 = (ps[q][1] - mu) * inv * g.y + bt.y;
        float v2 = (ps[q][2] - mu) * inv * g.z + bt.z;
        float v3 = (ps[q][3] - mu) * inv * g.w + bt.w;
        pacc += v0 * w.x + v1 * w.y + v2 * w.z + v3 * w.w;
        union { bf16 bb[4]; ushort4 u; } pk;
        pk.bb[0] = (bf16)v0; pk.bb[1] = (bf16)v1; pk.bb[2] = (bf16)v2; pk.bb[3] = (bf16)v3;
        *(ushort4*)(psn + (size_t)atom * PS_DIM + p * 4) = pk.u;
    }
    #pragma unroll
    for (int o = 32; o > 0; o >>= 1) pacc += __shfl_down(pacc, o);
    if ((t & 63) == 0) red2[wv] = pacc;
    __syncthreads();
    if (t == 0) psl[atom] = red2[0] + red2[1] + red2[2] + red2[3];
}

// ------------------------------------------------- bf16 MFMA GEMM: H = act(A @ Bt^T)
// A: M x K row-major bf16; Bt: Nc x K row-major bf16; H: M x Nc bf16.
// Staging via global_load_lds width=16 (m97 ladder step 3). LDS layout is
// lane-contiguous (chunk L -> LDS bytes [16L,16L+16)) as the instruction needs.
template<bool SILU>
__global__ __launch_bounds__(256) void gemm_bt_kernel(
    const bf16* __restrict__ A, const bf16* __restrict__ Bt,
    bf16* __restrict__ H, int M, int Nc, int K)
{
    __shared__ bf16 As[128 * 32];
    __shared__ bf16 Bs[128 * 32];
    int tid = threadIdx.x;
    int bm = blockIdx.x, bn = blockIdx.y;
    int wave = tid >> 6, lane = tid & 63;
    int wm = (wave >> 1) * 64, wn = (wave & 1) * 64;
    int lm = lane & 15, quad = lane >> 4;

    floatx4 acc[4][4] = {};
    const int rowA0 = bm * 128, rowB0 = bn * 128;

    for (int k0 = 0; k0 < K; k0 += 32) {
        #pragma unroll
        for (int s = 0; s < 2; ++s) {
            int L = tid + s * 256;            // 512 16B-chunks per tile
            int row = L >> 2, ch = (L & 3) * 8;
            // wave-uniform LDS base for this (stage, wave) segment:
            int lbase = (s * 256 + wave * 64) * 16;
            g2lds16(&A[(size_t)(rowA0 + row) * K + k0 + ch], (char*)As + lbase);
            g2lds16(&Bt[(size_t)(rowB0 + row) * K + k0 + ch], (char*)Bs + lbase);
        }
        __syncthreads();
        bf16x8 af[4], bfr[4];
        #pragma unroll
        for (int mi = 0; mi < 4; ++mi)
            af[mi] = *(const bf16x8*)(&As[(wm + mi * 16 + lm) * 32 + quad * 8]);
        #pragma unroll
        for (int ni = 0; ni < 4; ++ni)
            bfr[ni] = *(const bf16x8*)(&Bs[(wn + ni * 16 + lm) * 32 + quad * 8]);
        #pragma unroll
        for (int mi = 0; mi < 4; ++mi)
            #pragma unroll
            for (int ni = 0; ni < 4; ++ni)
                acc[mi][ni] = __builtin_amdgcn_mfma_f32_16x16x32_bf16(
                    af[mi], bfr[ni], acc[mi][ni], 0, 0, 0);
        __syncthreads();
    }

    #pragma unroll
    for (int mi = 0; mi < 4; ++mi) {
        #pragma unroll
        for (int ni = 0; ni < 4; ++ni) {
            #pragma unroll
            for (int r = 0; r < 4; ++r) {
                int row = rowA0 + wm + mi * 16 + quad * 4 + r;
                int col = rowB0 + wn + ni * 16 + lm;
                float v = acc[mi][ni][r];
                if (SILU) v = v / (1.0f + __expf(-v));
                H[(size_t)row * Nc + col] = (bf16)v;
            }
        }
    }
}

// ------------------------------------------------- psnn = h2 @ W3 ; e_atom = psl + psnn
__global__ __launch_bounds__(256) void psnn_kernel(
    const bf16* __restrict__ h2, const float* __restrict__ W3,
    const float* __restrict__ psl, float* __restrict__ e_atom)
{
    int atom = blockIdx.x * 4 + (threadIdx.x >> 6);
    int lane = threadIdx.x & 63;
    const bf16* h = h2 + (size_t)atom * H1_DIM;
    float s = 0.0f;
    #pragma unroll
    for (int q = 0; q < 16; ++q) {
        int k = lane + 64 * q;
        s += (float)h[k] * W3[k];
    }
    #pragma unroll
    for (int o = 32; o > 0; o >>= 1) s += __shfl_down(s, o);
    if (lane == 0) e_atom[atom] = psl[atom] + s;
}

// ------------------------------------------------- per-batch finalize
__global__ __launch_bounds__(128) void final_kernel(
    const float* __restrict__ e_atom, const int* __restrict__ numbers,
    const float* __restrict__ Wcomp, float* __restrict__ out)
{
    int b = blockIdx.x, t = threadIdx.x;  // 128 threads = atoms per batch
    __shared__ float sh[2];
    __shared__ int cnt[S_SPEC];
    if (t < S_SPEC) cnt[t] = 0;
    __syncthreads();
    int a = b * 128 + t;
    float e = e_atom[a];
    atomicAdd(&cnt[numbers[a]], 1);
    #pragma unroll
    for (int o = 32; o > 0; o >>= 1) e += __shfl_down(e, o);
    if ((t & 63) == 0) sh[t >> 6] = e;
    __syncthreads();
    if (t == 0) {
        float r = (sh[0] + sh[1]) * (1.0f / 128.0f);
        #pragma unroll
        for (int s = 0; s < S_SPEC; ++s) r += (float)cnt[s] * Wcomp[s];
        out[b] = r;
    }
}

extern "C" void kernel_launch(void* const* d_in, const int* in_sizes, int n_in,
                              void* d_out, int out_size, void* d_ws, size_t ws_size,
                              hipStream_t stream)
{
    const float* positions = (const float*)d_in[0];
    const float* cells     = (const float*)d_in[1];
    const int*   numbers   = (const int*)d_in[2];
    const int*   ei        = (const int*)d_in[3];
    const float* eo        = (const float*)d_in[4];
    const int*   batch     = (const int*)d_in[5];
    const float* gamma     = (const float*)d_in[6];
    const float* beta      = (const float*)d_in[7];
    const float* W_ps      = (const float*)d_in[8];
    const float* W1        = (const float*)d_in[9];
    const float* W2        = (const float*)d_in[10];
    const float* W3        = (const float*)d_in[11];
    const float* W_comp    = (const float*)d_in[12];
    float* out = (float*)d_out;

    char* ws = (char*)d_ws;
    float* c    = (float*)ws;  ws += (size_t)N_ATOMS * S_SPEC * 128 * 4;   // 16 MB
    bf16*  psn  = (bf16*)ws;   ws += (size_t)N_ATOMS * PS_DIM * 2;         // 64 MB
    bf16*  h1   = (bf16*)ws;   ws += (size_t)N_ATOMS * H1_DIM * 2;         // 16 MB
    bf16*  h2   = (bf16*)ws;   ws += (size_t)N_ATOMS * H1_DIM * 2;         // 16 MB
    bf16*  Wt1  = (bf16*)ws;   ws += (size_t)H1_DIM * PS_DIM * 2;          // 8 MB
    bf16*  Wt2  = (bf16*)ws;   ws += (size_t)H1_DIM * H1_DIM * 2;          // 2 MB
    float* psl  = (float*)ws;  ws += (size_t)N_ATOMS * 4;
    float* e_at = (float*)ws;  ws += (size_t)N_ATOMS * 4;

    // Aliased scratch (consumed before their hosts are written):
    //  - bucket (4 MB) aliases psn  : read by accum_kernel, psn written later by atom_ps
    //  - cnt/start/cursor (96 KB) alias h1 : read through accum, h1 written later by gemm1
    float4* bucket = (float4*)psn;
    int* cnt    = (int*)h1;
    int* start  = cnt + N_ATOMS;
    int* cursor = start + N_ATOMS;

    hipMemsetAsync(cnt, 0, N_ATOMS * sizeof(int), stream);

    hist_kernel<<<E_EDGES / 256, 256, 0, stream>>>(ei, cnt);
    scan_kernel<<<1, 1024, 0, stream>>>(cnt, start, cursor);
    scatter_kernel<<<E_EDGES / 256, 256, 0, stream>>>(
        positions, cells, numbers, ei, eo, batch, cursor, bucket);
    accum_kernel<<<N_ATOMS / 4, 256, 0, stream>>>(bucket, start, cursor, c);

    transpose_convert<<<dim3(PS_DIM / 32, H1_DIM / 32), 256, 0, stream>>>(
        W1, Wt1, PS_DIM, H1_DIM);
    transpose_convert<<<dim3(H1_DIM / 32, H1_DIM / 32), 256, 0, stream>>>(
        W2, Wt2, H1_DIM, H1_DIM);

    atom_ps_kernel<<<N_ATOMS, 256, 0, stream>>>(c, gamma, beta, W_ps, psn, psl);

    gemm_bt_kernel<true><<<dim3(N_ATOMS / 128, H1_DIM / 128), 256, 0, stream>>>(
        psn, Wt1, h1, N_ATOMS, H1_DIM, PS_DIM);
    gemm_bt_kernel<true><<<dim3(N_ATOMS / 128, H1_DIM / 128), 256, 0, stream>>>(
        h1, Wt2, h2, N_ATOMS, H1_DIM, H1_DIM);

    psnn_kernel<<<N_ATOMS / 4, 256, 0, stream>>>(h2, W3, psl, e_at);
    final_kernel<<<B_BATCH, 128, 0, stream>>>(e_at, numbers, W_comp, out);
}

// Round 4
// 317.985 us; speedup vs baseline: 5.6548x; 1.0916x over previous
//
#include <hip/hip_runtime.h>
#include <hip/hip_bf16.h>
#include <math.h>

#define N_ATOMS 8192
#define B_BATCH 64
#define E_EDGES 262144
#define S_SPEC 4
#define NMAX 8
#define PS_DIM 4096
#define H1_DIM 1024
#define CUTR 5.0f
#define PI_F 3.14159265358979f

typedef __bf16 bf16;
typedef bf16 bf16x8 __attribute__((ext_vector_type(8)));
typedef float floatx4 __attribute__((ext_vector_type(4)));

// async global->LDS, 16B per lane; LDS dest = wave-uniform base + lane*16
__device__ __forceinline__ void g2lds16(const void* g, void* l) {
    __builtin_amdgcn_global_load_lds(
        (const __attribute__((address_space(1))) void*)g,
        (__attribute__((address_space(3))) void*)l, 16, 0, 0);
}

// ---------------------------------------------------------------- histogram
__global__ __launch_bounds__(256) void hist_kernel(
    const int* __restrict__ ei, int* __restrict__ cnt)
{
    int e = blockIdx.x * 256 + threadIdx.x;
    atomicAdd(&cnt[ei[e]], 1);
}

// ---------------------------------------------------------------- scan
__global__ __launch_bounds__(1024) void scan_kernel(
    const int* __restrict__ cnt, int* __restrict__ start, int* __restrict__ cursor)
{
    int t = threadIdx.x;
    int v[8];
    int tot = 0;
    #pragma unroll
    for (int k = 0; k < 8; ++k) { v[k] = cnt[t * 8 + k]; tot += v[k]; }
    int lane = t & 63, wv = t >> 6;
    int inc = tot;
    #pragma unroll
    for (int o = 1; o < 64; o <<= 1) {
        int n = __shfl_up(inc, o);
        if (lane >= o) inc += n;
    }
    __shared__ int wsum[16];
    __shared__ int woff[16];
    if (lane == 63) wsum[wv] = inc;
    __syncthreads();
    if (t == 0) {
        int a = 0;
        for (int w = 0; w < 16; ++w) { woff[w] = a; a += wsum[w]; }
    }
    __syncthreads();
    int ex = woff[wv] + inc - tot;
    #pragma unroll
    for (int k = 0; k < 8; ++k) {
        start[t * 8 + k] = ex;
        cursor[t * 8 + k] = ex;
        ex += v[k];
    }
}

// ---------------------------------------------------------------- scatter
__global__ __launch_bounds__(256) void scatter_kernel(
    const float* __restrict__ pos, const float* __restrict__ cells,
    const int* __restrict__ numbers, const int* __restrict__ ei,
    const float* __restrict__ eo, const int* __restrict__ batch,
    int* __restrict__ cursor, float4* __restrict__ bucket)
{
    int e = blockIdx.x * 256 + threadIdx.x;
    int i = ei[e];
    int j = ei[E_EDGES + e];
    int b = batch[i];
    const float* cell = cells + b * 9;
    float o0 = eo[e * 3 + 0], o1 = eo[e * 3 + 1], o2 = eo[e * 3 + 2];
    float rv[3];
    #pragma unroll
    for (int d = 0; d < 3; ++d) {
        float shift = o0 * cell[0 * 3 + d] + o1 * cell[1 * 3 + d] + o2 * cell[2 * 3 + d];
        rv[d] = pos[j * 3 + d] - pos[i * 3 + d] + shift;
    }
    float r2 = rv[0] * rv[0] + rv[1] * rv[1] + rv[2] * rv[2] + 1e-12f;
    if (r2 >= CUTR * CUTR) return;   // fc == 0 -> zero contribution
    int sp = numbers[j];
    int slot = atomicAdd(&cursor[i], 1);
    bucket[slot] = make_float4(rv[0], rv[1], rv[2], __int_as_float(sp));
}

// ---------------------------------------------------------------- accumulate
// One wave per atom; lane owns c[atom*512 + lane*8 ..+7]. Zero atomics/barriers.
__global__ __launch_bounds__(256) void accum_kernel(
    const float4* __restrict__ bucket, const int* __restrict__ start,
    const int* __restrict__ endp, float* __restrict__ c)
{
    int wv = threadIdx.x >> 6, lane = threadIdx.x & 63;
    int atom = blockIdx.x * 4 + wv;

    int sp_l = lane >> 4;
    float nf = (float)(((lane >> 1) & 7) + 1);
    int par = lane & 1;

    float acc[8] = {};
    int s0 = start[atom], s1 = endp[atom];
    for (int base = s0; base < s1; base += 64) {
        int cnt = s1 - base; if (cnt > 64) cnt = 64;
        int idx = base + lane; if (idx >= s1) idx = s1 - 1;
        float4 d = bucket[idx];
        for (int e = 0; e < cnt; ++e) {
            float dx = __shfl(d.x, e);
            float dy = __shfl(d.y, e);
            float dz = __shfl(d.z, e);
            int sp = __float_as_int(__shfl(d.w, e));

            float r2 = dx * dx + dy * dy + dz * dz + 1e-12f;
            float r = sqrtf(r2);
            float inv_r = 1.0f / r;
            float a1 = PI_F * r * (1.0f / CUTR);
            float fc = 0.5f * (__cosf(a1) + 1.0f);
            float rn = fc * inv_r * __sinf(nf * a1);
            rn = (sp == sp_l) ? rn : 0.0f;

            float x = dx * inv_r, y = dy * inv_r, z = dz * inv_r;
            float x2 = x * x, y2 = y * y, z2 = z * z;
            float Ys[8];
            if (par == 0) {
                Ys[0] = 0.28209479f;
                Ys[1] = 0.48860251f * y;
                Ys[2] = 0.48860251f * z;
                Ys[3] = 0.48860251f * x;
                Ys[4] = 1.09254843f * x * y;
                Ys[5] = 1.09254843f * y * z;
                Ys[6] = 0.31539157f * (3.0f * z2 - 1.0f);
                Ys[7] = 1.09254843f * x * z;
            } else {
                Ys[0] = 0.54627422f * (x2 - y2);
                Ys[1] = 0.59004359f * y * (3.0f * x2 - y2);
                Ys[2] = 2.89061144f * x * y * z;
                Ys[3] = 0.45704579f * y * (5.0f * z2 - 1.0f);
                Ys[4] = 0.37317633f * z * (5.0f * z2 - 3.0f);
                Ys[5] = 0.45704579f * x * (5.0f * z2 - 1.0f);
                Ys[6] = 1.44530572f * z * (x2 - y2);
                Ys[7] = 0.59004359f * x * (x2 - 3.0f * y2);
            }
            #pragma unroll
            for (int k = 0; k < 8; ++k) acc[k] += rn * Ys[k];
        }
    }

    float* dst = c + (size_t)atom * 512 + lane * 8;
    *(float4*)(dst + 0) = make_float4(acc[0], acc[1], acc[2], acc[3]);
    *(float4*)(dst + 4) = make_float4(acc[4], acc[5], acc[6], acc[7]);
}

// ------------------------------------------------- fp32 -> bf16 transpose, chunk-swizzled
// Wt[n][k] = W[k][n], stored with 16B chunk c of each 128B segment at c^(n&7).
__global__ __launch_bounds__(256) void transpose_convert(
    const float* __restrict__ W, bf16* __restrict__ Wt, int K, int Nc)
{
    __shared__ float t[32][33];
    int k0 = blockIdx.x * 32, n0 = blockIdx.y * 32;
    int tx = threadIdx.x & 31, ty = threadIdx.x >> 5;  // ty in [0,8)
    #pragma unroll
    for (int r = 0; r < 32; r += 8)
        t[ty + r][tx] = W[(size_t)(k0 + ty + r) * Nc + n0 + tx];
    __syncthreads();
    if (threadIdx.x < 128) {
        int nl = threadIdx.x >> 2, cc = threadIdx.x & 3;   // row-local, chunk-local
        int n = n0 + nl;
        union { bf16 b[8]; uint4 u; } pk;
        #pragma unroll
        for (int jj = 0; jj < 8; ++jj) pk.b[jj] = (bf16)t[cc * 8 + jj][nl];
        int gc = (k0 >> 3) + cc;                        // global 16B-chunk index
        int gcs = (gc & ~7) | ((gc & 7) ^ (n & 7));     // swizzled
        *(uint4*)((char*)Wt + (size_t)n * K * 2 + (size_t)gcs * 16) = pk.u;
    }
}

// ------------------------------------------------- per-atom PS + layernorm + psl
// psn emitted bf16, chunk-swizzled per row (key = atom&7).
__global__ __launch_bounds__(256) void atom_ps_kernel(
    const float* __restrict__ c, const float* __restrict__ gamma,
    const float* __restrict__ beta, const float* __restrict__ Wps,
    bf16* __restrict__ psn, float* __restrict__ psl)
{
    int atom = blockIdx.x;
    int t = threadIdx.x;
    __shared__ float cl[512];
    __shared__ bf16 ps_s[PS_DIM];
    __shared__ float red[8];
    __shared__ float red2[4];

    const float* ca = c + (size_t)atom * 512;
    ((float2*)cl)[t] = ((const float2*)ca)[t];
    __syncthreads();

    int y = t & 31;
    int xb = t >> 5;
    float cy[16];
    #pragma unroll
    for (int m = 0; m < 16; ++m) cy[m] = cl[y * 16 + m];

    float ps[4][4];
    float sum = 0.0f, sumsq = 0.0f;
    #pragma unroll
    for (int q = 0; q < 4; ++q) {
        int x = xb + 8 * q;
        const float* cx = &cl[x * 16];
        float s0 = cx[0] * cy[0];
        float s1 = 0.0f, s2 = 0.0f, s3 = 0.0f;
        #pragma unroll
        for (int m = 1; m < 4; ++m) s1 += cx[m] * cy[m];
        #pragma unroll
        for (int m = 4; m < 9; ++m) s2 += cx[m] * cy[m];
        #pragma unroll
        for (int m = 9; m < 16; ++m) s3 += cx[m] * cy[m];
        ps[q][0] = s0; ps[q][1] = s1; ps[q][2] = s2; ps[q][3] = s3;
        sum += s0 + s1 + s2 + s3;
        sumsq += s0 * s0 + s1 * s1 + s2 * s2 + s3 * s3;
    }
    #pragma unroll
    for (int o = 32; o > 0; o >>= 1) {
        sum += __shfl_down(sum, o);
        sumsq += __shfl_down(sumsq, o);
    }
    int wv = t >> 6;
    if ((t & 63) == 0) { red[wv] = sum; red[4 + wv] = sumsq; }
    __syncthreads();
    float tot = red[0] + red[1] + red[2] + red[3];
    float totsq = red[4] + red[5] + red[6] + red[7];
    float mu = tot * (1.0f / PS_DIM);
    float var = totsq * (1.0f / PS_DIM) - mu * mu;
    float inv = rsqrtf(var + 1e-5f);

    float pacc = 0.0f;
    #pragma unroll
    for (int q = 0; q < 4; ++q) {
        int p = t + 256 * q;
        float4 g = *(const float4*)(gamma + p * 4);
        float4 bt = *(const float4*)(beta + p * 4);
        float4 w = *(const float4*)(Wps + p * 4);
        float v0 = (ps[q][0] - mu) * inv * g.x + bt.x;
        float v1 = (ps[q][1] - mu) * inv * g.y + bt.y;
        float v2 = (ps[q][2] - mu) * inv * g.z + bt.z;
        float v3 = (ps[q][3] - mu) * inv * g.w + bt.w;
        pacc += v0 * w.x + v1 * w.y + v2 * w.z + v3 * w.w;
        union { bf16 bb[4]; ushort4 u; } pk;
        pk.bb[0] = (bf16)v0; pk.bb[1] = (bf16)v1; pk.bb[2] = (bf16)v2; pk.bb[3] = (bf16)v3;
        *(ushort4*)(ps_s + p * 4) = pk.u;
    }
    __syncthreads();
    // swizzled 16B-chunk store of the row (512 chunks, 2 per thread)
    char* rowp = (char*)psn + (size_t)atom * (PS_DIM * 2);
    int key = atom & 7;
    #pragma unroll
    for (int q2 = 0; q2 < 2; ++q2) {
        int gc = t + 256 * q2;
        int gcs = (gc & ~7) | ((gc & 7) ^ key);
        *(uint4*)(rowp + (size_t)gcs * 16) = *(uint4*)((char*)ps_s + (size_t)gc * 16);
    }
    #pragma unroll
    for (int o = 32; o > 0; o >>= 1) pacc += __shfl_down(pacc, o);
    if ((t & 63) == 0) red2[wv] = pacc;
    __syncthreads();
    if (t == 0) psl[atom] = red2[0] + red2[1] + red2[2] + red2[3];
}

// ------------------------------------------------- bf16 MFMA GEMM: H = silu(A @ Bt^T)
// A: M x K row-major bf16, chunk-swizzled (16B chunk c of each 128B segment at
// c^(row&7)); Bt: Nc x K, same swizzle. BK=64; staging is a verbatim row-segment
// copy via global_load_lds so LDS inherits the swizzle; fragment reads XOR the
// chunk index -> conflict-free (2 lanes/bank). Output H: bf16, optionally
// re-swizzled (when it feeds the next GEMM as A).
template<bool SWZ_OUT>
__global__ __launch_bounds__(256) void gemm_bt_kernel(
    const bf16* __restrict__ A, const bf16* __restrict__ Bt,
    bf16* __restrict__ H, int M, int Nc, int K)
{
    __shared__ char smem[32768];
    bf16* As = (bf16*)smem;              // 128 rows x 128B
    bf16* Bs = (bf16*)(smem + 16384);
    int tid = threadIdx.x;
    int bm = blockIdx.x, bn = blockIdx.y;
    int wave = tid >> 6, lane = tid & 63;
    int wm = (wave >> 1) * 64, wn = (wave & 1) * 64;
    int lm = lane & 15, quad = lane >> 4;

    floatx4 acc[4][4] = {};
    const int rowA0 = bm * 128, rowB0 = bn * 128;
    const size_t strideB = (size_t)K * 2;   // row bytes
    const char* Ab = (const char*)A + (size_t)rowA0 * strideB;
    const char* Bb = (const char*)Bt + (size_t)rowB0 * strideB;

    for (int k0 = 0; k0 < K; k0 += 64) {
        #pragma unroll
        for (int s = 0; s < 4; ++s) {
            int L = s * 256 + tid;              // 1024 chunks: row = L>>3, c = L&7
            int row = L >> 3, boff = (L & 7) * 16;
            int lbase = (s * 256 + wave * 64) * 16;   // wave-uniform LDS base
            g2lds16(Ab + (size_t)row * strideB + k0 * 2 + boff, smem + lbase);
            g2lds16(Bb + (size_t)row * strideB + k0 * 2 + boff, smem + 16384 + lbase);
        }
        __syncthreads();
        #pragma unroll
        for (int h = 0; h < 2; ++h) {
            bf16x8 af[4], bfr[4];
            #pragma unroll
            for (int mi = 0; mi < 4; ++mi) {
                int r = wm + mi * 16 + lm;
                int ch = (h * 4 + quad) ^ (lm & 7);
                af[mi] = *(const bf16x8*)(smem + r * 128 + ch * 16);
            }
            #pragma unroll
            for (int ni = 0; ni < 4; ++ni) {
                int r = wn + ni * 16 + lm;
                int ch = (h * 4 + quad) ^ (lm & 7);
                bfr[ni] = *(const bf16x8*)(smem + 16384 + r * 128 + ch * 16);
            }
            #pragma unroll
            for (int mi = 0; mi < 4; ++mi)
                #pragma unroll
                for (int ni = 0; ni < 4; ++ni)
                    acc[mi][ni] = __builtin_amdgcn_mfma_f32_16x16x32_bf16(
                        af[mi], bfr[ni], acc[mi][ni], 0, 0, 0);
        }
        __syncthreads();
    }

    // Epilogue: SiLU, round-trip C through LDS, coalesced (swizzled) 16B stores.
    bf16* Cs = (bf16*)smem;                  // 128 x 128 bf16 = 32KB
    #pragma unroll
    for (int mi = 0; mi < 4; ++mi)
        #pragma unroll
        for (int ni = 0; ni < 4; ++ni)
            #pragma unroll
            for (int r = 0; r < 4; ++r) {
                int row = wm + mi * 16 + quad * 4 + r;
                int col = wn + ni * 16 + lm;
                float v = acc[mi][ni][r];
                v = v / (1.0f + __expf(-v));
                Cs[row * 128 + col] = (bf16)v;
            }
    __syncthreads();
    const size_t strideH = (size_t)Nc * 2;
    #pragma unroll
    for (int c0 = 0; c0 < 8; ++c0) {
        int L = c0 * 256 + tid;              // 2048 chunks: row = L>>4, cc = L&15
        int row = L >> 4, cc = L & 15;
        int gc = bn * 16 + cc;
        int gcs = SWZ_OUT ? ((gc & ~7) | ((cc & 7) ^ (row & 7))) : gc;
        *(uint4*)((char*)H + (size_t)(rowA0 + row) * strideH + (size_t)gcs * 16) =
            *(uint4*)((char*)Cs + (size_t)L * 16);
    }
}

// ------------------------------------------------- psnn = h2 @ W3 ; e_atom = psl + psnn
__global__ __launch_bounds__(256) void psnn_kernel(
    const bf16* __restrict__ h2, const float* __restrict__ W3,
    const float* __restrict__ psl, float* __restrict__ e_atom)
{
    int atom = blockIdx.x * 4 + (threadIdx.x >> 6);
    int lane = threadIdx.x & 63;
    const bf16* h = h2 + (size_t)atom * H1_DIM;
    float s = 0.0f;
    #pragma unroll
    for (int q = 0; q < 16; ++q) {
        int k = lane + 64 * q;
        s += (float)h[k] * W3[k];
    }
    #pragma unroll
    for (int o = 32; o > 0; o >>= 1) s += __shfl_down(s, o);
    if (lane == 0) e_atom[atom] = psl[atom] + s;
}

// ------------------------------------------------- per-batch finalize
__global__ __launch_bounds__(128) void final_kernel(
    const float* __restrict__ e_atom, const int* __restrict__ numbers,
    const float* __restrict__ Wcomp, float* __restrict__ out)
{
    int b = blockIdx.x, t = threadIdx.x;  // 128 threads = atoms per batch
    __shared__ float sh[2];
    __shared__ int cnt[S_SPEC];
    if (t < S_SPEC) cnt[t] = 0;
    __syncthreads();
    int a = b * 128 + t;
    float e = e_atom[a];
    atomicAdd(&cnt[numbers[a]], 1);
    #pragma unroll
    for (int o = 32; o > 0; o >>= 1) e += __shfl_down(e, o);
    if ((t & 63) == 0) sh[t >> 6] = e;
    __syncthreads();
    if (t == 0) {
        float r = (sh[0] + sh[1]) * (1.0f / 128.0f);
        #pragma unroll
        for (int s = 0; s < S_SPEC; ++s) r += (float)cnt[s] * Wcomp[s];
        out[b] = r;
    }
}

extern "C" void kernel_launch(void* const* d_in, const int* in_sizes, int n_in,
                              void* d_out, int out_size, void* d_ws, size_t ws_size,
                              hipStream_t stream)
{
    const float* positions = (const float*)d_in[0];
    const float* cells     = (const float*)d_in[1];
    const int*   numbers   = (const int*)d_in[2];
    const int*   ei        = (const int*)d_in[3];
    const float* eo        = (const float*)d_in[4];
    const int*   batch     = (const int*)d_in[5];
    const float* gamma     = (const float*)d_in[6];
    const float* beta      = (const float*)d_in[7];
    const float* W_ps      = (const float*)d_in[8];
    const float* W1        = (const float*)d_in[9];
    const float* W2        = (const float*)d_in[10];
    const float* W3        = (const float*)d_in[11];
    const float* W_comp    = (const float*)d_in[12];
    float* out = (float*)d_out;

    char* ws = (char*)d_ws;
    float* c    = (float*)ws;  ws += (size_t)N_ATOMS * S_SPEC * 128 * 4;   // 16 MB
    bf16*  psn  = (bf16*)ws;   ws += (size_t)N_ATOMS * PS_DIM * 2;         // 64 MB
    bf16*  h1   = (bf16*)ws;   ws += (size_t)N_ATOMS * H1_DIM * 2;         // 16 MB
    bf16*  h2   = (bf16*)ws;   ws += (size_t)N_ATOMS * H1_DIM * 2;         // 16 MB
    bf16*  Wt1  = (bf16*)ws;   ws += (size_t)H1_DIM * PS_DIM * 2;          // 8 MB
    bf16*  Wt2  = (bf16*)ws;   ws += (size_t)H1_DIM * H1_DIM * 2;          // 2 MB
    float* psl  = (float*)ws;  ws += (size_t)N_ATOMS * 4;
    float* e_at = (float*)ws;  ws += (size_t)N_ATOMS * 4;

    // Aliased scratch (consumed before their hosts are written):
    float4* bucket = (float4*)psn;
    int* cnt    = (int*)h1;
    int* start  = cnt + N_ATOMS;
    int* cursor = start + N_ATOMS;

    hipMemsetAsync(cnt, 0, N_ATOMS * sizeof(int), stream);

    hist_kernel<<<E_EDGES / 256, 256, 0, stream>>>(ei, cnt);
    scan_kernel<<<1, 1024, 0, stream>>>(cnt, start, cursor);
    scatter_kernel<<<E_EDGES / 256, 256, 0, stream>>>(
        positions, cells, numbers, ei, eo, batch, cursor, bucket);
    accum_kernel<<<N_ATOMS / 4, 256, 0, stream>>>(bucket, start, cursor, c);

    transpose_convert<<<dim3(PS_DIM / 32, H1_DIM / 32), 256, 0, stream>>>(
        W1, Wt1, PS_DIM, H1_DIM);
    transpose_convert<<<dim3(H1_DIM / 32, H1_DIM / 32), 256, 0, stream>>>(
        W2, Wt2, H1_DIM, H1_DIM);

    atom_ps_kernel<<<N_ATOMS, 256, 0, stream>>>(c, gamma, beta, W_ps, psn, psl);

    gemm_bt_kernel<true><<<dim3(N_ATOMS / 128, H1_DIM / 128), 256, 0, stream>>>(
        psn, Wt1, h1, N_ATOMS, H1_DIM, PS_DIM);
    gemm_bt_kernel<false><<<dim3(N_ATOMS / 128, H1_DIM / 128), 256, 0, stream>>>(
        h1, Wt2, h2, N_ATOMS, H1_DIM, H1_DIM);

    psnn_kernel<<<N_ATOMS / 4, 256, 0, stream>>>(h2, W3, psl, e_at);
    final_kernel<<<B_BATCH, 128, 0, stream>>>(e_at, numbers, W_comp, out);
}